// Round 2
// baseline (153.632 us; speedup 1.0000x reference)
//
#include <hip/hip_runtime.h>

#define V_IN 40962
#define V_OUT 163842
#define NCH 64
#define CTOT 256

typedef float f2 __attribute__((ext_vector_type(2)));

// ---------------- transpose: x[2][256][V_IN] -> xT[2][V_IN][256] ----------------
__global__ __launch_bounds__(256) void transpose_k(const float* __restrict__ x,
                                                   float* __restrict__ xT) {
    __shared__ float tile[64][65];   // [v][c]
    const int b  = blockIdx.z;
    const int v0 = blockIdx.x * 64;
    const int c0 = blockIdx.y * 64;
    const int t  = threadIdx.x;
    const int i  = t & 15;
    const int s  = t >> 4;           // 0..15
#pragma unroll
    for (int p = 0; p < 4; ++p) {
        int c = s + 16 * p;          // works for blockDim 256: s in 0..15
        int v = 4 * i;
        float4 val = {0.f, 0.f, 0.f, 0.f};
        const float* src = x + ((size_t)b * CTOT + c0 + c) * V_IN + v0 + v;
        if (v0 + v + 3 < V_IN) {
            val = *(const float4*)src;
        } else {
            if (v0 + v     < V_IN) val.x = src[0];
            if (v0 + v + 1 < V_IN) val.y = src[1];
            if (v0 + v + 2 < V_IN) val.z = src[2];
            if (v0 + v + 3 < V_IN) val.w = src[3];
        }
        tile[v    ][c] = val.x;
        tile[v + 1][c] = val.y;
        tile[v + 2][c] = val.z;
        tile[v + 3][c] = val.w;
    }
    __syncthreads();
#pragma unroll
    for (int p = 0; p < 4; ++p) {
        int v = s + 16 * p;
        if (v0 + v < V_IN) {
            float4 val;
            val.x = tile[v][4 * i];
            val.y = tile[v][4 * i + 1];
            val.z = tile[v][4 * i + 2];
            val.w = tile[v][4 * i + 3];
            *(float4*)(xT + ((size_t)b * V_IN + v0 + v) * CTOT + c0 + 4 * i) = val;
        }
    }
}

// ---------------- per-output attention math ----------------
__device__ __forceinline__ float attn_one(const float4& a0, const float4& a1,
                                          const f2 (&cs2)[8][4]) {
    float vals[8] = {a0.x, a1.x, a0.y, a1.y, a0.z, a1.z, a0.w, a1.w};
    f2 s2[4];
#pragma unroll
    for (int j = 0; j < 4; ++j) s2[j] = cs2[0][j] * vals[0];
#pragma unroll
    for (int k = 1; k < 8; ++k) {
        f2 vk = {vals[k], vals[k]};
#pragma unroll
        for (int j = 0; j < 4; ++j)
            s2[j] = __builtin_elementwise_fma(vk, cs2[k][j], s2[j]);
    }
    float m = fmaxf(fmaxf(fmaxf(s2[0].x, s2[0].y), fmaxf(s2[1].x, s2[1].y)),
                    fmaxf(fmaxf(s2[2].x, s2[2].y), fmaxf(s2[3].x, s2[3].y)));
    const float C = 0.18033688011112042f;   // log2(e)/8 : softmax(s/8) via exp2
    f2 sum2 = {0.f, 0.f}, num2 = {0.f, 0.f};
#pragma unroll
    for (int j = 0; j < 4; ++j) {
        f2 tt = (s2[j] - m) * C;
        f2 e;
        e.x = exp2f(tt.x);
        e.y = exp2f(tt.y);
        sum2 += e;
        f2 v2 = {vals[2 * j], vals[2 * j + 1]};
        num2 = __builtin_elementwise_fma(v2, e, num2);
    }
    float sum = sum2.x + sum2.y;
    float num = num2.x + num2.y;
    return num * __builtin_amdgcn_rcpf(sum);
}

// ---------------- fused gather + attn + softmax + weighted sum ----------------
template <int DIRECT>
__global__ __launch_bounds__(256) void fused_k(const float* __restrict__ xsrc,
                                               const float* __restrict__ coeffs,
                                               const int* __restrict__ map,
                                               float* __restrict__ out) {
    __shared__ float otile[2][NCH][33];   // half-tile: 32 v (+1 pad)
    __shared__ int   jmap[128];

    const int tid    = threadIdx.x;
    const int lane   = tid & 63;
    const int w      = tid >> 6;
    const int b      = w >> 1;
    const int parity = w & 1;
    const int vbase  = blockIdx.x * 64;
    const bool full  = (vbase + 64 <= V_OUT);

    if (tid < 128) {
        int gi = vbase * 2 + tid;
        jmap[tid] = (gi < 2 * V_OUT) ? map[gi] : 0;
    }

    // lane-uniform coeff loads -> SGPRs, as float2 pairs cs2[k][j] = coeffs[k*8 + 2j..+1]
    f2 cs2[8][4];
#pragma unroll
    for (int k = 0; k < 8; ++k)
#pragma unroll
        for (int j = 0; j < 4; ++j)
            cs2[k][j] = *(const f2*)(coeffs + k * 8 + 2 * j);

    __syncthreads();

    const int c = lane;
    const float* xb = xsrc + (size_t)b * V_IN * CTOT + 4 * c;   // DIRECT=0 base

    for (int h = 0; h < 2; ++h) {
        if (full) {
#pragma unroll 2
            for (int i = 0; i < 16; ++i) {
                const int vh = parity + 2 * i;
                const int vl = h * 32 + vh;
                const int j0 = jmap[2 * vl];
                const int j1 = jmap[2 * vl + 1];
                float4 a0, a1;
                if (DIRECT) {
#pragma unroll
                    for (int e = 0; e < 4; ++e) {
                        ((float*)&a0)[e] = xsrc[((size_t)b * CTOT + 4 * c + e) * V_IN + j0];
                        ((float*)&a1)[e] = xsrc[((size_t)b * CTOT + 4 * c + e) * V_IN + j1];
                    }
                } else {
                    a0 = *(const float4*)(xb + (size_t)j0 * CTOT);
                    a1 = *(const float4*)(xb + (size_t)j1 * CTOT);
                }
                otile[b][c][vh] = attn_one(a0, a1, cs2);
            }
        } else {
            for (int i = 0; i < 16; ++i) {
                const int vh = parity + 2 * i;
                const int vl = h * 32 + vh;
                float r = 0.f;
                if (vbase + vl < V_OUT) {
                    const int j0 = jmap[2 * vl];
                    const int j1 = jmap[2 * vl + 1];
                    float4 a0, a1;
                    if (DIRECT) {
#pragma unroll
                        for (int e = 0; e < 4; ++e) {
                            ((float*)&a0)[e] = xsrc[((size_t)b * CTOT + 4 * c + e) * V_IN + j0];
                            ((float*)&a1)[e] = xsrc[((size_t)b * CTOT + 4 * c + e) * V_IN + j1];
                        }
                    } else {
                        a0 = *(const float4*)(xb + (size_t)j0 * CTOT);
                        a1 = *(const float4*)(xb + (size_t)j1 * CTOT);
                    }
                    r = attn_one(a0, a1, cs2);
                }
                otile[b][c][vh] = r;
            }
        }
        __syncthreads();

        // write-out half h: 128 rows (b,c) x 32 v, float2 per lane
        if (full) {
#pragma unroll
            for (int t2 = 0; t2 < 8; ++t2) {
                int rr = w * 32 + (lane >> 4) + 4 * t2;
                int bb = rr >> 6, cc = rr & 63;
                int vv = (lane & 15) * 2;
                f2 val = {otile[bb][cc][vv], otile[bb][cc][vv + 1]};
                *(f2*)(out + ((size_t)bb * NCH + cc) * V_OUT + vbase + h * 32 + vv) = val;
            }
        } else {
            for (int t2 = 0; t2 < 8; ++t2) {
                int rr = w * 32 + (lane >> 4) + 4 * t2;
                int bb = rr >> 6, cc = rr & 63;
                int vv = (lane & 15) * 2;
#pragma unroll
                for (int q = 0; q < 2; ++q) {
                    int v = vbase + h * 32 + vv + q;
                    if (v < V_OUT) out[((size_t)bb * NCH + cc) * V_OUT + v] = otile[bb][cc][vv + q];
                }
            }
        }
        __syncthreads();
    }
}

extern "C" void kernel_launch(void* const* d_in, const int* in_sizes, int n_in,
                              void* d_out, int out_size, void* d_ws, size_t ws_size,
                              hipStream_t stream) {
    const float* x      = (const float*)d_in[0];
    const float* coeffs = (const float*)d_in[1];
    const int*   map    = (const int*)d_in[2];
    float*       out    = (float*)d_out;

    const size_t xT_bytes = (size_t)2 * V_IN * CTOT * sizeof(float);
    const int nblocks = (V_OUT + 63) / 64;

    if (ws_size >= xT_bytes) {
        float* xT = (float*)d_ws;
        dim3 tgrid((V_IN + 63) / 64, CTOT / 64, 2);
        transpose_k<<<tgrid, dim3(256), 0, stream>>>(x, xT);
        fused_k<0><<<nblocks, 256, 0, stream>>>(xT, coeffs, map, out);
    } else {
        fused_k<1><<<nblocks, 256, 0, stream>>>(x, coeffs, map, out);
    }
}

// Round 4
// 111.474 us; speedup vs baseline: 1.3782x; 1.3782x over previous
//
#include <hip/hip_runtime.h>

#define V_IN 40962
#define V_OUT 163842
#define NCH 64
#define CTOT 256

typedef float    f2 __attribute__((ext_vector_type(2)));
typedef float    f4 __attribute__((ext_vector_type(4)));
typedef _Float16 h4 __attribute__((ext_vector_type(4)));

// ---------------- transpose+downcast: x[2][256][V_IN] f32 -> xT[2][V_IN][256] fp16 ----------------
__global__ __launch_bounds__(256) void transpose_k(const float* __restrict__ x,
                                                   _Float16* __restrict__ xT) {
    __shared__ float tile[64][65];   // [v][c]
    const int b  = blockIdx.z;
    const int v0 = blockIdx.x * 64;
    const int c0 = blockIdx.y * 64;
    const int t  = threadIdx.x;
    const int i  = t & 15;
    const int s  = t >> 4;           // 0..15
#pragma unroll
    for (int p = 0; p < 4; ++p) {
        int c = s + 16 * p;
        int v = 4 * i;
        f4 val = {0.f, 0.f, 0.f, 0.f};
        const float* src = x + ((size_t)b * CTOT + c0 + c) * V_IN + v0 + v;
        if (v0 + v + 3 < V_IN) {
            val = __builtin_nontemporal_load((const f4*)src);
        } else {
            if (v0 + v     < V_IN) val.x = src[0];
            if (v0 + v + 1 < V_IN) val.y = src[1];
            if (v0 + v + 2 < V_IN) val.z = src[2];
            if (v0 + v + 3 < V_IN) val.w = src[3];
        }
        tile[v    ][c] = val.x;
        tile[v + 1][c] = val.y;
        tile[v + 2][c] = val.z;
        tile[v + 3][c] = val.w;
    }
    __syncthreads();
#pragma unroll
    for (int p = 0; p < 4; ++p) {
        int v = s + 16 * p;
        if (v0 + v < V_IN) {
            h4 val;
            val.x = (_Float16)tile[v][4 * i];
            val.y = (_Float16)tile[v][4 * i + 1];
            val.z = (_Float16)tile[v][4 * i + 2];
            val.w = (_Float16)tile[v][4 * i + 3];
            *(h4*)(xT + ((size_t)b * V_IN + v0 + v) * CTOT + c0 + 4 * i) = val;
        }
    }
}

// ---------------- per-output attention math (f32 internal) ----------------
__device__ __forceinline__ float attn_one(float vals[8], const f2 (&cs2)[8][4]) {
    f2 s2[4];
#pragma unroll
    for (int j = 0; j < 4; ++j) s2[j] = cs2[0][j] * vals[0];
#pragma unroll
    for (int k = 1; k < 8; ++k) {
        f2 vk = {vals[k], vals[k]};
#pragma unroll
        for (int j = 0; j < 4; ++j)
            s2[j] = __builtin_elementwise_fma(vk, cs2[k][j], s2[j]);
    }
    float m = fmaxf(fmaxf(fmaxf(s2[0].x, s2[0].y), fmaxf(s2[1].x, s2[1].y)),
                    fmaxf(fmaxf(s2[2].x, s2[2].y), fmaxf(s2[3].x, s2[3].y)));
    const float C = 0.18033688011112042f;   // log2(e)/8
    f2 sum2 = {0.f, 0.f}, num2 = {0.f, 0.f};
#pragma unroll
    for (int j = 0; j < 4; ++j) {
        f2 tt = (s2[j] - m) * C;
        f2 e;
        e.x = __builtin_amdgcn_exp2f(tt.x);
        e.y = __builtin_amdgcn_exp2f(tt.y);
        sum2 += e;
        f2 v2 = {vals[2 * j], vals[2 * j + 1]};
        num2 = __builtin_elementwise_fma(v2, e, num2);
    }
    float sum = sum2.x + sum2.y;
    float num = num2.x + num2.y;
    return num * __builtin_amdgcn_rcpf(sum);
}

__device__ __forceinline__ void unpack2(const h4& a0, const h4& a1, float (&vals)[8]) {
    vals[0] = (float)a0.x; vals[1] = (float)a1.x;
    vals[2] = (float)a0.y; vals[3] = (float)a1.y;
    vals[4] = (float)a0.z; vals[5] = (float)a1.z;
    vals[6] = (float)a0.w; vals[7] = (float)a1.w;
}

// ---------------- fused gather + attn + softmax + weighted sum ----------------
// DIRECT=0: xsrc16 = xT[b][v_in][256] fp16.  DIRECT=1: fall back to raw f32 x.
template <int DIRECT>
__global__ __launch_bounds__(256) void fused_k(const _Float16* __restrict__ xsrc16,
                                               const float* __restrict__ xsrc32,
                                               const float* __restrict__ coeffs,
                                               const int* __restrict__ map,
                                               float* __restrict__ out) {
    __shared__ float otile[2][NCH][33];
    __shared__ int   jmap[128];

    const int tid    = threadIdx.x;
    const int lane   = tid & 63;
    const int w      = tid >> 6;
    const int b      = w >> 1;
    const int parity = w & 1;
    const int vbase  = blockIdx.x * 64;
    const bool full  = (vbase + 64 <= V_OUT);

    if (tid < 128) {
        int gi = vbase * 2 + tid;
        jmap[tid] = (gi < 2 * V_OUT) ? map[gi] : 0;
    }

    f2 cs2[8][4];
#pragma unroll
    for (int k = 0; k < 8; ++k)
#pragma unroll
        for (int j = 0; j < 4; ++j)
            cs2[k][j] = *(const f2*)(coeffs + k * 8 + 2 * j);

    __syncthreads();

    const int c = lane;
    const _Float16* xb = xsrc16 + (size_t)b * V_IN * CTOT + 4 * c;

    for (int h = 0; h < 2; ++h) {
        if (full && !DIRECT) {
            // software-pipelined: loads for i+1 in flight during compute of i
            int vl = h * 32 + parity;
            int j0 = jmap[2 * vl], j1 = jmap[2 * vl + 1];
            h4 a0 = *(const h4*)(xb + (size_t)j0 * CTOT);
            h4 a1 = *(const h4*)(xb + (size_t)j1 * CTOT);
#pragma unroll 2
            for (int i = 0; i < 16; ++i) {
                h4 b0 = a0, b1 = a1;
                if (i < 15) {
                    int k0 = jmap[2 * (vl + 2)], k1 = jmap[2 * (vl + 2) + 1];
                    b0 = *(const h4*)(xb + (size_t)k0 * CTOT);
                    b1 = *(const h4*)(xb + (size_t)k1 * CTOT);
                }
                float vals[8];
                unpack2(a0, a1, vals);
                otile[b][c][vl - h * 32] = attn_one(vals, cs2);
                a0 = b0; a1 = b1; vl += 2;
            }
        } else {
            for (int i = 0; i < 16; ++i) {
                const int vh = parity + 2 * i;
                const int vl = h * 32 + vh;
                float r = 0.f;
                if (vbase + vl < V_OUT) {
                    const int j0 = jmap[2 * vl];
                    const int j1 = jmap[2 * vl + 1];
                    float vals[8];
                    if (DIRECT) {
#pragma unroll
                        for (int e = 0; e < 4; ++e) {
                            vals[2 * e]     = xsrc32[((size_t)b * CTOT + 4 * c + e) * V_IN + j0];
                            vals[2 * e + 1] = xsrc32[((size_t)b * CTOT + 4 * c + e) * V_IN + j1];
                        }
                    } else {
                        h4 a0 = *(const h4*)(xb + (size_t)j0 * CTOT);
                        h4 a1 = *(const h4*)(xb + (size_t)j1 * CTOT);
                        unpack2(a0, a1, vals);
                    }
                    r = attn_one(vals, cs2);
                }
                otile[b][c][vl - h * 32] = r;
            }
        }
        __syncthreads();

        if (full) {
#pragma unroll
            for (int t2 = 0; t2 < 8; ++t2) {
                int rr = w * 32 + (lane >> 4) + 4 * t2;
                int bb = rr >> 6, cc = rr & 63;
                int vv = (lane & 15) * 2;
                f2 val = {otile[bb][cc][vv], otile[bb][cc][vv + 1]};
                __builtin_nontemporal_store(val,
                    (f2*)(out + ((size_t)bb * NCH + cc) * V_OUT + vbase + h * 32 + vv));
            }
        } else {
            for (int t2 = 0; t2 < 8; ++t2) {
                int rr = w * 32 + (lane >> 4) + 4 * t2;
                int bb = rr >> 6, cc = rr & 63;
                int vv = (lane & 15) * 2;
#pragma unroll
                for (int q = 0; q < 2; ++q) {
                    int v = vbase + h * 32 + vv + q;
                    if (v < V_OUT) out[((size_t)bb * NCH + cc) * V_OUT + v] = otile[bb][cc][vv + q];
                }
            }
        }
        __syncthreads();
    }
}

extern "C" void kernel_launch(void* const* d_in, const int* in_sizes, int n_in,
                              void* d_out, int out_size, void* d_ws, size_t ws_size,
                              hipStream_t stream) {
    const float* x      = (const float*)d_in[0];
    const float* coeffs = (const float*)d_in[1];
    const int*   map    = (const int*)d_in[2];
    float*       out    = (float*)d_out;

    const size_t xT_bytes = (size_t)2 * V_IN * CTOT * sizeof(_Float16);
    const int nblocks = (V_OUT + 63) / 64;

    if (ws_size >= xT_bytes) {
        _Float16* xT = (_Float16*)d_ws;
        dim3 tgrid((V_IN + 63) / 64, CTOT / 64, 2);
        transpose_k<<<tgrid, dim3(256), 0, stream>>>(x, xT);
        fused_k<0><<<nblocks, 256, 0, stream>>>(xT, nullptr, coeffs, map, out);
    } else {
        fused_k<1><<<nblocks, 256, 0, stream>>>(nullptr, x, coeffs, map, out);
    }
}

// Round 5
// 108.454 us; speedup vs baseline: 1.4166x; 1.0278x over previous
//
#include <hip/hip_runtime.h>

#define V_IN 40962
#define V_OUT 163842
#define NCH 64
#define CTOT 256

typedef float    f2 __attribute__((ext_vector_type(2)));
typedef float    f4 __attribute__((ext_vector_type(4)));
typedef _Float16 h2 __attribute__((ext_vector_type(2)));
typedef _Float16 h4 __attribute__((ext_vector_type(4)));

// ---------------- transpose+downcast: x[2][256][V_IN] f32 -> xT[2][V_IN][256] fp16 ----------------
__global__ __launch_bounds__(256) void transpose_k(const float* __restrict__ x,
                                                   _Float16* __restrict__ xT) {
    __shared__ float tile[64][65];   // [v][c]
    const int b  = blockIdx.z;
    const int v0 = blockIdx.x * 64;
    const int c0 = blockIdx.y * 64;
    const int t  = threadIdx.x;
    const int i  = t & 15;
    const int s  = t >> 4;           // 0..15
#pragma unroll
    for (int p = 0; p < 4; ++p) {
        int c = s + 16 * p;
        int v = 4 * i;
        f4 val = {0.f, 0.f, 0.f, 0.f};
        const float* src = x + ((size_t)b * CTOT + c0 + c) * V_IN + v0 + v;
        if (v0 + v + 3 < V_IN) {
            val = __builtin_nontemporal_load((const f4*)src);
        } else {
            if (v0 + v     < V_IN) val.x = src[0];
            if (v0 + v + 1 < V_IN) val.y = src[1];
            if (v0 + v + 2 < V_IN) val.z = src[2];
            if (v0 + v + 3 < V_IN) val.w = src[3];
        }
        tile[v    ][c] = val.x;
        tile[v + 1][c] = val.y;
        tile[v + 2][c] = val.z;
        tile[v + 3][c] = val.w;
    }
    __syncthreads();
#pragma unroll
    for (int p = 0; p < 4; ++p) {
        int v = s + 16 * p;
        if (v0 + v < V_IN) {
            h4 val;
            val.x = (_Float16)tile[v][4 * i];
            val.y = (_Float16)tile[v][4 * i + 1];
            val.z = (_Float16)tile[v][4 * i + 2];
            val.w = (_Float16)tile[v][4 * i + 3];
            *(h4*)(xT + ((size_t)b * V_IN + v0 + v) * CTOT + c0 + 4 * i) = val;
        }
    }
}

// ---------------- per-output attention math (f32 internal) ----------------
__device__ __forceinline__ float attn_one(const float vals[8], const f2 (&cs2)[8][4]) {
    f2 s2[4];
#pragma unroll
    for (int j = 0; j < 4; ++j) s2[j] = cs2[0][j] * vals[0];
#pragma unroll
    for (int k = 1; k < 8; ++k) {
        f2 vk = {vals[k], vals[k]};
#pragma unroll
        for (int j = 0; j < 4; ++j)
            s2[j] = __builtin_elementwise_fma(vk, cs2[k][j], s2[j]);
    }
    f2 m01 = __builtin_elementwise_max(s2[0], s2[1]);
    f2 m23 = __builtin_elementwise_max(s2[2], s2[3]);
    f2 mm  = __builtin_elementwise_max(m01, m23);
    float m = fmaxf(mm.x, mm.y);
    const float C = 0.18033688011112042f;   // log2(e)/8
    float nmC = m * (-C);
    f2 C2   = {C, C};
    f2 nmC2 = {nmC, nmC};
    f2 sum2 = {0.f, 0.f}, num2 = {0.f, 0.f};
#pragma unroll
    for (int j = 0; j < 4; ++j) {
        f2 tt = __builtin_elementwise_fma(s2[j], C2, nmC2);   // s*C - m*C
        f2 e;
        e.x = __builtin_amdgcn_exp2f(tt.x);
        e.y = __builtin_amdgcn_exp2f(tt.y);
        sum2 += e;
        f2 v2 = {vals[2 * j], vals[2 * j + 1]};
        num2 = __builtin_elementwise_fma(v2, e, num2);
    }
    float sum = sum2.x + sum2.y;
    float num = num2.x + num2.y;
    return num * __builtin_amdgcn_rcpf(sum);
}

__device__ __forceinline__ void unpack2(const h4& a0, const h4& a1, float (&vals)[8]) {
    vals[0] = (float)a0.x; vals[1] = (float)a1.x;
    vals[2] = (float)a0.y; vals[3] = (float)a1.y;
    vals[4] = (float)a0.z; vals[5] = (float)a1.z;
    vals[6] = (float)a0.w; vals[7] = (float)a1.w;
}

// ---------------- fused gather + attn + softmax + weighted sum ----------------
// DIRECT=0: xsrc16 = xT[b][v_in][256] fp16.  DIRECT=1: fall back to raw f32 x.
template <int DIRECT>
__global__ __launch_bounds__(256) void fused_k(const _Float16* __restrict__ xsrc16,
                                               const float* __restrict__ xsrc32,
                                               const float* __restrict__ coeffs,
                                               const int* __restrict__ map,
                                               float* __restrict__ out) {
    __shared__ _Float16 otile[2][NCH][34];   // fp16 half-tile (even pad for h2 alignment)
    __shared__ int      jmap[128];

    const int tid    = threadIdx.x;
    const int lane   = tid & 63;
    const int w      = tid >> 6;
    const int b      = w >> 1;
    const int parity = w & 1;
    const int vbase  = blockIdx.x * 64;
    const bool full  = (vbase + 64 <= V_OUT);

    if (tid < 128) {
        int gi = vbase * 2 + tid;
        jmap[tid] = (gi < 2 * V_OUT) ? map[gi] : 0;
    }

    f2 cs2[8][4];
#pragma unroll
    for (int k = 0; k < 8; ++k)
#pragma unroll
        for (int j = 0; j < 4; ++j)
            cs2[k][j] = *(const f2*)(coeffs + k * 8 + 2 * j);

    __syncthreads();

    const int c = lane;
    const _Float16* xb = xsrc16 + (size_t)b * V_IN * CTOT + 4 * c;

    for (int h = 0; h < 2; ++h) {
        const int vl0 = h * 32 + parity;     // vl(i) = vl0 + 2*i

        if (full && !DIRECT) {
            h4 A[4][2], B[4][2];

            // load chunk ck (iterations ck*4 .. ck*4+3) into buf
#define LOAD_CHUNK(buf, ck)                                                        \
            _Pragma("unroll")                                                      \
            for (int q = 0; q < 4; ++q) {                                          \
                int2 jp = *(const int2*)&jmap[2 * (vl0 + 2 * ((ck) * 4 + q))];     \
                int j0 = __builtin_amdgcn_readfirstlane(jp.x);                     \
                int j1 = __builtin_amdgcn_readfirstlane(jp.y);                     \
                buf[q][0] = *(const h4*)(xb + (size_t)j0 * CTOT);                  \
                buf[q][1] = *(const h4*)(xb + (size_t)j1 * CTOT);                  \
            }

#define COMP_CHUNK(buf, ck)                                                        \
            _Pragma("unroll")                                                      \
            for (int q = 0; q < 4; ++q) {                                          \
                float vals[8];                                                     \
                unpack2(buf[q][0], buf[q][1], vals);                               \
                otile[b][c][parity + 2 * ((ck) * 4 + q)] =                         \
                    (_Float16)attn_one(vals, cs2);                                 \
            }

            LOAD_CHUNK(A, 0)
            LOAD_CHUNK(B, 1)
            COMP_CHUNK(A, 0)
            LOAD_CHUNK(A, 2)
            COMP_CHUNK(B, 1)
            LOAD_CHUNK(B, 3)
            COMP_CHUNK(A, 2)
            COMP_CHUNK(B, 3)
#undef LOAD_CHUNK
#undef COMP_CHUNK
        } else {
            for (int i = 0; i < 16; ++i) {
                const int vh = parity + 2 * i;
                const int vl = h * 32 + vh;
                float r = 0.f;
                if (vbase + vl < V_OUT) {
                    const int j0 = jmap[2 * vl];
                    const int j1 = jmap[2 * vl + 1];
                    float vals[8];
                    if (DIRECT) {
#pragma unroll
                        for (int e = 0; e < 4; ++e) {
                            vals[2 * e]     = xsrc32[((size_t)b * CTOT + 4 * c + e) * V_IN + j0];
                            vals[2 * e + 1] = xsrc32[((size_t)b * CTOT + 4 * c + e) * V_IN + j1];
                        }
                    } else {
                        h4 a0 = *(const h4*)(xb + (size_t)j0 * CTOT);
                        h4 a1 = *(const h4*)(xb + (size_t)j1 * CTOT);
                        unpack2(a0, a1, vals);
                    }
                    r = attn_one(vals, cs2);
                }
                otile[b][c][vh] = (_Float16)r;
            }
        }
        __syncthreads();

        if (full) {
#pragma unroll
            for (int t2 = 0; t2 < 8; ++t2) {
                int rr = w * 32 + (lane >> 4) + 4 * t2;
                int bb = rr >> 6, cc = rr & 63;
                int vv = (lane & 15) * 2;
                h2 hv = *(const h2*)&otile[bb][cc][vv];
                f2 val;
                val.x = (float)hv.x;
                val.y = (float)hv.y;
                __builtin_nontemporal_store(val,
                    (f2*)(out + ((size_t)bb * NCH + cc) * V_OUT + vbase + h * 32 + vv));
            }
        } else {
            for (int t2 = 0; t2 < 8; ++t2) {
                int rr = w * 32 + (lane >> 4) + 4 * t2;
                int bb = rr >> 6, cc = rr & 63;
                int vv = (lane & 15) * 2;
#pragma unroll
                for (int q = 0; q < 2; ++q) {
                    int v = vbase + h * 32 + vv + q;
                    if (v < V_OUT)
                        out[((size_t)bb * NCH + cc) * V_OUT + v] = (float)otile[bb][cc][vv + q];
                }
            }
        }
        __syncthreads();
    }
}

extern "C" void kernel_launch(void* const* d_in, const int* in_sizes, int n_in,
                              void* d_out, int out_size, void* d_ws, size_t ws_size,
                              hipStream_t stream) {
    const float* x      = (const float*)d_in[0];
    const float* coeffs = (const float*)d_in[1];
    const int*   map    = (const int*)d_in[2];
    float*       out    = (float*)d_out;

    const size_t xT_bytes = (size_t)2 * V_IN * CTOT * sizeof(_Float16);
    const int nblocks = (V_OUT + 63) / 64;

    if (ws_size >= xT_bytes) {
        _Float16* xT = (_Float16*)d_ws;
        dim3 tgrid((V_IN + 63) / 64, CTOT / 64, 2);
        transpose_k<<<tgrid, dim3(256), 0, stream>>>(x, xT);
        fused_k<0><<<nblocks, 256, 0, stream>>>(xT, nullptr, coeffs, map, out);
    } else {
        fused_k<1><<<nblocks, 256, 0, stream>>>(nullptr, x, coeffs, map, out);
    }
}